// Round 10
// 1478.266 us; speedup vs baseline: 7.1217x; 1.0946x over previous
//
#include <hip/hip_runtime.h>
#include <stdint.h>

// ---------------- problem constants ----------------
static constexpr int N_   = 1026;
static constexpr int DX_  = 4096;
static constexpr int DG_  = 4096;
static constexpr int H0_  = 4096;
static constexpr int H1_  = 2048;
static constexpr int H2_  = 1024;
static constexpr int OUTS_= 512;
static constexpr int NL_  = 10;
static constexpr int JH_  = 2048;
static constexpr int E_   = 32832;
static constexpr int K_   = 128;
static constexpr int INS_ = DX_ + DG_;              // 8192
static constexpr int CAT2_= H0_ + H1_ + H2_;        // 7168

static constexpr int MP_   = 1152;   // 1026 padded to 9*128
static constexpr int KP1_  = 1056;   // 1026 padded to 33*32

typedef _Float16 f16;
typedef __attribute__((ext_vector_type(8))) _Float16 f16x8;
typedef __attribute__((ext_vector_type(4))) _Float16 f16x4;
typedef __attribute__((ext_vector_type(4))) float    f32x4;

#define AS1C(p) ((const __attribute__((address_space(1))) unsigned int*)(p))
#define AS3(p)  ((__attribute__((address_space(3))) unsigned int*)(p))

__device__ __forceinline__ void gload16(const f16* g, f16* s) {
    __builtin_amdgcn_global_load_lds(AS1C(g), AS3(s), 16, 0, 0);
}

// XCD-aware bijective tile swizzle (m204): same-bx tiles contiguous per XCD.
__device__ __forceinline__ void swz_tile(int gx, int gy, int& bx, int& by) {
    int nwg = gx * gy;
    int hid = blockIdx.x + gx * blockIdx.y;   // hw dispatch order within z-slice
    int xcd = hid & 7, seq = hid >> 3;
    int q = nwg >> 3, r = nwg & 7;
    int lin = (xcd < r ? xcd * (q + 1) : r * (q + 1) + (xcd - r) * q) + seq;
    bx = lin / gy;  by = lin - bx * gy;
}

// =====================================================================
//  MFMA GEMM.
//  DUAL: fp32 via fp16 hi/lo split (3 MFMA/K-slice, 4 planes, 64KB dbuf).
//  !DUAL,!WIDE: single fp16, 128x128 tile, 32KB dbuf, 4 blocks/CU.
//  WIDE: single fp16, 128x256 tile (24KB/step for 2x output: staging-
//  bytes-bound regime -> 25% fewer bytes), 48KB dbuf.
//  8 waves (512 thr); counted vmcnt keeps next-step loads in flight.
// =====================================================================
template<bool RELU, bool DUAL, bool WIDE>
__global__ __launch_bounds__(512, (DUAL || WIDE) ? 4 : 8)
void gemm_f16x2(int M, int Nc, int Kt, int chunkSteps,
                const f16* __restrict__ Ah, const f16* __restrict__ Al, int lda,
                const f16* __restrict__ Bh, const f16* __restrict__ Bl, int ldb,
                const float* __restrict__ bias, float alpha,
                const float* __restrict__ D, int ldd, float dscale,
                float* __restrict__ C, int ldc,
                f16* __restrict__ oAh, f16* __restrict__ oAl, int ldoa,
                f16* __restrict__ oBh, f16* __restrict__ oBl, int ldob,
                float* __restrict__ P, int Mp, int Ncp)
{
    static_assert(!(DUAL && WIDE), "dual+wide unsupported");
    constexpr int BUFE = DUAL ? 16384 : (WIDE ? 12288 : 8192);  // f16/buffer
    constexpr int BN   = WIDE ? 256 : 128;
    constexpr int NJ   = WIDE ? 8 : 4;
    constexpr int BOFF = DUAL ? 8192 : 4096;
    __shared__ __align__(16) f16 sm[2 * BUFE];

    const int tid  = threadIdx.x;
    const int lane = tid & 63, w = tid >> 6;
    const int wr = w >> 1, wc = w & 1;
    int bx, by; swz_tile(gridDim.x, gridDim.y, bx, by);
    const int bm = by * 128, bn = bx * BN;
    const int z  = blockIdx.z;

    const int totalSteps = Kt >> 5;
    const int sBeg = z * chunkSteps;
    int nst = totalSteps - sBeg; if (nst > chunkSteps) nst = chunkSteps;

    const int srow  = w * 16 + (tid & 15);
    const int skoff = ((tid >> 4) & 3) * 8;
    const size_t arow  = (size_t)(bm + srow) * lda + skoff;
    const size_t brow  = (size_t)(bn + srow) * ldb + skoff;
    const size_t brow2 = WIDE ? ((size_t)(bn + 128 + srow) * ldb + skoff) : 0;
    const int wslot = w * 512;
    const int fr = (lane >> 4) * 128 + (lane & 15) * 8;
    const int iaBase = wr * 1024 + fr;
    const int ibBase = BOFF + wc * (WIDE ? 4096 : 2048) + fr;

    f32x4 acc[2][NJ] = {};

    auto stage = [&](int buf, size_t ka) {
        f16* s0 = sm + buf * BUFE;
        gload16(Ah + arow + ka, s0 + wslot);
        if constexpr (DUAL) gload16(Al + arow + ka, s0 + 4096 + wslot);
        gload16(Bh + brow + ka, s0 + BOFF + wslot);
        if constexpr (DUAL) gload16(Bl + brow + ka, s0 + BOFF + 4096 + wslot);
        if constexpr (WIDE) gload16(Bh + brow2 + ka, s0 + BOFF + 4096 + wslot);
    };

    if (nst > 0) {
        const size_t kb = (size_t)sBeg * 32;
        stage(0, kb);
        for (int s = 0; s < nst; ++s) {
            if (s + 1 < nst) {
                stage((s + 1) & 1, kb + (size_t)(s + 1) * 32);
                if constexpr (DUAL)
                    asm volatile("s_waitcnt vmcnt(4)\n\ts_barrier" ::: "memory");
                else if constexpr (WIDE)
                    asm volatile("s_waitcnt vmcnt(3)\n\ts_barrier" ::: "memory");
                else
                    asm volatile("s_waitcnt vmcnt(2)\n\ts_barrier" ::: "memory");
            } else {
                asm volatile("s_waitcnt vmcnt(0)\n\ts_barrier" ::: "memory");
            }
            const f16* sb = sm + (s & 1) * BUFE;
            f16x8 ah[2], al[2], bh4[NJ], bl4[NJ];
            #pragma unroll
            for (int i = 0; i < 2; ++i) {
                ah[i] = *(const f16x8*)&sb[iaBase + i * 512];
                if constexpr (DUAL) al[i] = *(const f16x8*)&sb[4096 + iaBase + i * 512];
            }
            #pragma unroll
            for (int j = 0; j < NJ; ++j) {
                bh4[j] = *(const f16x8*)&sb[ibBase + j * 512];
                if constexpr (DUAL) bl4[j] = *(const f16x8*)&sb[4096 + ibBase + j * 512];
            }
            #pragma unroll
            for (int i = 0; i < 2; ++i)
                #pragma unroll
                for (int j = 0; j < NJ; ++j) {
                    acc[i][j] = __builtin_amdgcn_mfma_f32_16x16x32_f16(ah[i], bh4[j], acc[i][j], 0, 0, 0);
                    if constexpr (DUAL) {
                        acc[i][j] = __builtin_amdgcn_mfma_f32_16x16x32_f16(ah[i], bl4[j], acc[i][j], 0, 0, 0);
                        acc[i][j] = __builtin_amdgcn_mfma_f32_16x16x32_f16(al[i], bh4[j], acc[i][j], 0, 0, 0);
                    }
                }
            if (s + 1 < nst) asm volatile("s_barrier" ::: "memory");
        }
    }

    const int er = (lane >> 4) * 4;
    const int ec = lane & 15;
    const int m00 = bm + wr * 32, n00 = bn + wc * (WIDE ? 128 : 64);

    if (P) {
        float* Pz = P + (size_t)z * Mp * Ncp;
        #pragma unroll
        for (int mi = 0; mi < 2; ++mi)
            #pragma unroll
            for (int nj = 0; nj < NJ; ++nj) {
                const int gc = n00 + nj * 16 + ec;
                const int gr = m00 + mi * 16 + er;
                float* p = Pz + (size_t)gr * Ncp + gc;
                f32x4 a = acc[mi][nj];
                #pragma unroll
                for (int r = 0; r < 4; ++r) p[(size_t)r * Ncp] = a[r];
            }
        return;
    }

    #pragma unroll
    for (int mi = 0; mi < 2; ++mi) {
        #pragma unroll
        for (int nj = 0; nj < NJ; ++nj) {
            const int gcol = n00 + nj * 16 + ec;
            if (gcol >= Nc) continue;
            const float bv = bias ? bias[gcol] : 0.f;
            f32x4 a = acc[mi][nj];
            #pragma unroll
            for (int r = 0; r < 4; ++r) {
                const int grow = m00 + mi * 16 + er + r;
                if (grow >= M) continue;
                float val = alpha * a[r];
                if (D) val = fmaf(dscale, D[(size_t)grow * ldd + gcol], val);
                val += bv;
                if (RELU) val = fmaxf(val, 0.f);
                if (C) C[(size_t)grow * ldc + gcol] = val;
                if (oAh) {
                    f16 h = (f16)val;
                    oAh[(size_t)grow * ldoa + gcol] = h;
                    if (oAl) oAl[(size_t)grow * ldoa + gcol] = (f16)(val - (float)h);
                }
                if (oBh) {
                    f16 h = (f16)val;
                    oBh[(size_t)gcol * ldob + grow] = h;
                    if (oBl) oBl[(size_t)gcol * ldob + grow] = (f16)(val - (float)h);
                }
            }
        }
    }
}

// split-K reduce + epilogue (deterministic fixed z-order)
template<bool RELU>
__global__ __launch_bounds__(256)
void combine_k(int M, int Nc, int nz, int Mp, int Ncp,
               const float* __restrict__ P,
               const float* __restrict__ bias, float alpha,
               const float* __restrict__ D, int ldd, float dscale,
               float* __restrict__ C, int ldc,
               f16* __restrict__ oAh, f16* __restrict__ oAl, int ldoa,
               f16* __restrict__ oBh, f16* __restrict__ oBl, int ldob)
{
    unsigned idx = blockIdx.x * 256 + threadIdx.x;
    if (idx >= (unsigned)(M * Nc)) return;
    int row = idx / (unsigned)Nc, col = idx - row * Nc;
    const float* p = P + (size_t)row * Ncp + col;
    float s = 0.f;
    for (int zz = 0; zz < nz; ++zz) s += p[(size_t)zz * Mp * Ncp];
    float val = alpha * s;
    if (D) val = fmaf(dscale, D[(size_t)row * ldd + col], val);
    if (bias) val += bias[col];
    if (RELU) val = fmaxf(val, 0.f);
    if (C) C[(size_t)row * ldc + col] = val;
    if (oAh) {
        f16 h = (f16)val;
        oAh[(size_t)row * ldoa + col] = h;
        if (oAl) oAl[(size_t)row * ldoa + col] = (f16)(val - (float)h);
    }
    if (oBh) {
        f16 h = (f16)val;
        oBh[(size_t)col * ldob + row] = h;
        if (oBl) oBl[(size_t)col * ldob + row] = (f16)(val - (float)h);
    }
}

// =====================================================================
//  P-chain stage: SPLIT-K fused dual-role GEMM (partials only).
// =====================================================================
__global__ __launch_bounds__(512, 4)
void pchain_k(int roleBase, int split, int chunkSteps,
              const f16* __restrict__ uAh, const f16* __restrict__ uAl,
              const f16* __restrict__ sAh, const f16* __restrict__ sAl,
              const f16* __restrict__ Bh, const f16* __restrict__ Bl,
              float* __restrict__ Pp)
{
    __shared__ __align__(16) f16 sm[2][4][4096];
    const int tid  = threadIdx.x;
    const int lane = tid & 63, w = tid >> 6;
    const int wr = w >> 1, wc = w & 1;
    int bx, by; swz_tile(gridDim.x, gridDim.y, bx, by);
    const int bm = by * 128, bn = bx * 128;
    const int z = blockIdx.z;
    const int role = roleBase + z / split;
    const int sub  = z % split;
    const f16* Ah = (role == 0) ? uAh : sAh;
    const f16* Al = (role == 0) ? uAl : sAl;

    const int sBeg = sub * chunkSteps;
    int nst = KP1_ / 32 - sBeg; if (nst > chunkSteps) nst = chunkSteps;

    const int srow  = w * 16 + (tid & 15);
    const int skoff = ((tid >> 4) & 3) * 8;
    const size_t arow = (size_t)(bm + srow) * KP1_ + skoff;
    const size_t brow = (size_t)(bn + srow) * KP1_ + skoff;
    const int wslot = w * 512;
    const int fr = (lane >> 4) * 128 + (lane & 15) * 8;
    const int iaBase = wr * 1024 + fr;
    const int ibBase = wc * 2048 + fr;

    f32x4 acc[2][4] = {};

    auto stage = [&](int buf, size_t ka) {
        f16* s0 = (f16*)&sm[buf][0][0];
        gload16(Ah + arow + ka, s0 + wslot);
        gload16(Al + arow + ka, s0 + 4096 + wslot);
        gload16(Bh + brow + ka, s0 + 8192 + wslot);
        gload16(Bl + brow + ka, s0 + 12288 + wslot);
    };

    if (nst > 0) {
        const size_t kb = (size_t)sBeg * 32;
        stage(0, kb);
        for (int s = 0; s < nst; ++s) {
            if (s + 1 < nst) {
                stage((s + 1) & 1, kb + (size_t)(s + 1) * 32);
                asm volatile("s_waitcnt vmcnt(4)\n\ts_barrier" ::: "memory");
            } else {
                asm volatile("s_waitcnt vmcnt(0)\n\ts_barrier" ::: "memory");
            }
            const int b = s & 1;
            f16x8 ah[2], al[2], bh4[4], bl4[4];
            #pragma unroll
            for (int i = 0; i < 2; ++i) {
                ah[i]  = *(const f16x8*)&sm[b][0][iaBase + i * 512];
                al[i]  = *(const f16x8*)&sm[b][1][iaBase + i * 512];
            }
            #pragma unroll
            for (int j = 0; j < 4; ++j) {
                bh4[j] = *(const f16x8*)&sm[b][2][ibBase + j * 512];
                bl4[j] = *(const f16x8*)&sm[b][3][ibBase + j * 512];
            }
            #pragma unroll
            for (int i = 0; i < 2; ++i)
                #pragma unroll
                for (int j = 0; j < 4; ++j) {
                    acc[i][j] = __builtin_amdgcn_mfma_f32_16x16x32_f16(ah[i], bh4[j], acc[i][j], 0, 0, 0);
                    acc[i][j] = __builtin_amdgcn_mfma_f32_16x16x32_f16(ah[i], bl4[j], acc[i][j], 0, 0, 0);
                    acc[i][j] = __builtin_amdgcn_mfma_f32_16x16x32_f16(al[i], bh4[j], acc[i][j], 0, 0, 0);
                }
            if (s + 1 < nst) asm volatile("s_barrier" ::: "memory");
        }
    }

    float* Pz = Pp + (size_t)z * (1152 * 1152);
    const int er = (lane >> 4) * 4;
    const int ec = lane & 15;
    const int m00 = bm + wr * 32, n00 = bn + wc * 64;
    #pragma unroll
    for (int mi = 0; mi < 2; ++mi)
        #pragma unroll
        for (int nj = 0; nj < 4; ++nj) {
            const int gc = n00 + nj * 16 + ec;
            const int gr = m00 + mi * 16 + er;
            float* p = Pz + (size_t)gr * 1152 + gc;
            f32x4 a = acc[mi][nj];
            #pragma unroll
            for (int r = 0; r < 4; ++r) p[(size_t)r * 1152] = a[r];
        }
}

// P-chain combine: reduce split partials, apply both roles' epilogues.
__global__ __launch_bounds__(256)
void pchain_combine_k(int nz, int hasUpd, int hasSq, const float* __restrict__ Pp,
                      const float* __restrict__ PfIn, float* __restrict__ PfOut,
                      f16* __restrict__ oPh, f16* __restrict__ oPl,
                      float* __restrict__ XT,
                      f16* __restrict__ oAh, f16* __restrict__ oAl,
                      f16* __restrict__ oAth, f16* __restrict__ oAtl)
{
    unsigned idx = blockIdx.x * 256 + threadIdx.x;
    if (idx >= (unsigned)(N_ * N_)) return;
    int row = idx / (unsigned)N_, col = idx - row * N_;
    const size_t zs = (size_t)1152 * 1152;
    const size_t poff = (size_t)row * 1152 + col;
    int zb = 0;
    if (hasUpd) {
        float s = 0.f;
        for (int z = 0; z < nz; ++z) s += Pp[(size_t)(zb + z) * zs + poff];
        float val = s + PfIn[idx];
        PfOut[idx] = val;
        if (oPh) {
            f16 h = (f16)val, l = (f16)(val - (float)h);
            oPh[(size_t)row * KP1_ + col] = h;
            oPl[(size_t)row * KP1_ + col] = l;
        }
        if (XT) XT[(size_t)col * N_ + row] = val;
        zb += nz;
    }
    if (hasSq) {
        float s = 0.f;
        for (int z = 0; z < nz; ++z) s += Pp[(size_t)(zb + z) * zs + poff];
        f16 h = (f16)s, l = (f16)(s - (float)h);
        oAh[(size_t)row * KP1_ + col] = h;  oAl[(size_t)row * KP1_ + col] = l;
        oAth[(size_t)col * KP1_ + row] = h; oAtl[(size_t)col * KP1_ + row] = l;
    }
}

// A = 0.95*T, P_1 = I + A ; emit A-form, Bt-form, Pf fp32, P-A-form
__global__ void build_A_k(const float* __restrict__ zz, const float* __restrict__ dinv,
                          f16* __restrict__ aAh, f16* __restrict__ aAl,
                          f16* __restrict__ aBth, f16* __restrict__ aBtl,
                          float* __restrict__ Pf,
                          f16* __restrict__ pAh, f16* __restrict__ pAl)
{
    int idx = blockIdx.x * 256 + threadIdx.x;
    if (idx >= N_ * N_) return;
    int i = idx / N_, j = idx - i * N_;
    float diag = (i == j) ? 1.f : 0.f;
    float a = 0.95f * dinv[i] * (zz[idx] + diag) * dinv[j];
    f16 h = (f16)a, l = (f16)(a - (float)h);
    aAh[(size_t)i * KP1_ + j] = h;  aAl[(size_t)i * KP1_ + j] = l;
    aBth[(size_t)j * KP1_ + i] = h; aBtl[(size_t)j * KP1_ + i] = l;
    float p = a + diag;
    Pf[idx] = p;
    f16 ph = (f16)p, pl = (f16)(p - (float)ph);
    pAh[(size_t)i * KP1_ + j] = ph; pAl[(size_t)i * KP1_ + j] = pl;
}

// =====================================================================
//  Top-K via in-LDS bitonic sort of u64 keys (value desc, index asc),
//  then column-normalize. Reads X^T (coalesced rows).
// =====================================================================
__global__ __launch_bounds__(256)
void topk_sort_k(const float* __restrict__ XT, float* __restrict__ S)
{
    __shared__ uint64_t key[2048];
    __shared__ float red[4];
    const int j = blockIdx.x, t = threadIdx.x;
    for (int i = t; i < 2048; i += 256) {
        uint64_t kk;
        if (i < N_) {
            float v = XT[(size_t)j * N_ + i];
            unsigned u = __float_as_uint(v);
            unsigned sv = (u & 0x80000000u) ? ~u : (u | 0x80000000u);
            kk = ((uint64_t)(~sv) << 32) | (unsigned)i;
        } else kk = ~0ULL;
        key[i] = kk;
    }
    __syncthreads();
    for (int k = 2; k <= 2048; k <<= 1) {
        for (int jj = k >> 1; jj > 0; jj >>= 1) {
            #pragma unroll
            for (int q = 0; q < 8; ++q) {
                int i = t + q * 256;
                int ixj = i ^ jj;
                if (ixj > i) {
                    uint64_t a = key[i], b = key[ixj];
                    bool up = ((i & k) == 0);
                    if ((a > b) == up) { key[i] = b; key[ixj] = a; }
                }
            }
            __syncthreads();
        }
    }
    float val = 0.f; int idx = 0;
    if (t < K_) {
        uint64_t kk = key[t];
        unsigned sv = ~(unsigned)(kk >> 32);
        unsigned u = (sv & 0x80000000u) ? (sv & 0x7FFFFFFFu) : ~sv;
        val = __uint_as_float(u);
        idx = (int)(kk & 0xFFFFFFFFu);
    }
    float sm = (t < K_) ? val : 0.f;
    #pragma unroll
    for (int q = 32; q > 0; q >>= 1) sm += __shfl_xor(sm, q);
    if ((t & 63) == 0) red[t >> 6] = sm;
    __syncthreads();
    float cs = red[0] + red[1] + red[2] + red[3];
    if (cs == 0.f) cs = 1.f;
    if (t < K_) S[(size_t)idx * N_ + j] = val / cs;
}

// ---------------- conversion kernels (vectorized, l-plane optional) ----------------
__global__ void conv_A_k(const float* __restrict__ src, int R, int C, int lds,
                         f16* __restrict__ dh, f16* __restrict__ dl, int ldd,
                         int Rp, int Cp)
{
    size_t i4 = ((size_t)blockIdx.x * 256 + threadIdx.x) * 4;
    if (i4 >= (size_t)Rp * Cp) return;
    int r = (int)(i4 / Cp), c = (int)(i4 % Cp);
    float v[4] = {0.f, 0.f, 0.f, 0.f};
    if (r < R) {
        if (((lds & 3) == 0) && c + 3 < C) {
            float4 f = *(const float4*)&src[(size_t)r * lds + c];
            v[0] = f.x; v[1] = f.y; v[2] = f.z; v[3] = f.w;
        } else {
            #pragma unroll
            for (int q = 0; q < 4; ++q) v[q] = (c + q < C) ? src[(size_t)r * lds + c + q] : 0.f;
        }
    }
    f16x4 h, l;
    #pragma unroll
    for (int q = 0; q < 4; ++q) { h[q] = (f16)v[q]; l[q] = (f16)(v[q] - (float)h[q]); }
    *(f16x4*)&dh[(size_t)r * ldd + c] = h;
    if (dl) *(f16x4*)&dl[(size_t)r * ldd + c] = l;
}

__global__ __launch_bounds__(256)
void conv_Bt_k(const float* __restrict__ src, int K, int N,
               f16* __restrict__ dh, f16* __restrict__ dl, int ldk,
               int Kp, int Np)
{
    __shared__ float t[32][65];
    const int bk = blockIdx.x * 32, bn = blockIdx.y * 64;
    const int tid = threadIdx.x;
    {
        const int kk = tid >> 4;
        const int nn = (tid & 15) * 4;
        #pragma unroll
        for (int p = 0; p < 2; ++p) {
            int k = bk + kk + p * 16;
            float v[4] = {0.f, 0.f, 0.f, 0.f};
            if (k < K) {
                int n = bn + nn;
                if (((N & 3) == 0) && n + 3 < N) {
                    float4 f = *(const float4*)&src[(size_t)k * N + n];
                    v[0] = f.x; v[1] = f.y; v[2] = f.z; v[3] = f.w;
                } else {
                    #pragma unroll
                    for (int q = 0; q < 4; ++q) v[q] = (n + q < N) ? src[(size_t)k * N + n + q] : 0.f;
                }
            }
            #pragma unroll
            for (int q = 0; q < 4; ++q) t[kk + p * 16][nn + q] = v[q];
        }
    }
    __syncthreads();
    {
        const int nn0 = tid >> 3;
        const int k4  = (tid & 7) * 4;
        #pragma unroll
        for (int p = 0; p < 2; ++p) {
            int n = bn + nn0 + p * 32;
            int k = bk + k4;
            if (n < Np && k < Kp) {
                f16x4 h, l;
                #pragma unroll
                for (int q = 0; q < 4; ++q) {
                    float vv = t[k4 + q][nn0 + p * 32];
                    h[q] = (f16)vv; l[q] = (f16)(vv - (float)h[q]);
                }
                *(f16x4*)&dh[(size_t)n * ldk + k] = h;
                if (dl) *(f16x4*)&dl[(size_t)n * ldk + k] = l;
            }
        }
    }
}

__global__ void cat2_conv_k(const float* __restrict__ a, const float* __restrict__ b,
                            f16* __restrict__ dh, f16* __restrict__ dl)
{
    size_t i4 = ((size_t)blockIdx.x * 256 + threadIdx.x) * 4;
    if (i4 >= (size_t)MP_ * 8192) return;
    int r = (int)(i4 / 8192), c = (int)(i4 % 8192);
    float v[4] = {0.f, 0.f, 0.f, 0.f};
    if (r < N_) {
        const float* s = (c < 4096) ? &a[(size_t)r * 4096 + c] : &b[(size_t)r * 4096 + (c - 4096)];
        float4 f = *(const float4*)s;
        v[0] = f.x; v[1] = f.y; v[2] = f.z; v[3] = f.w;
    }
    f16x4 h, l;
    #pragma unroll
    for (int q = 0; q < 4; ++q) { h[q] = (f16)v[q]; l[q] = (f16)(v[q] - (float)h[q]); }
    *(f16x4*)&dh[i4] = h;
    *(f16x4*)&dl[i4] = l;
}

// zgx = fp16(z) + gx -> h-plane only (feeds single GEMM)
__global__ void zgx_conv_k(const f16* __restrict__ zh, const float* __restrict__ gx,
                           f16* __restrict__ dh)
{
    size_t i4 = ((size_t)blockIdx.x * 256 + threadIdx.x) * 4;
    if (i4 >= (size_t)MP_ * 4096) return;
    int r = (int)(i4 / 4096), c = (int)(i4 % 4096);
    f16x4 h = {};
    if (r < N_) {
        f16x4 zh4 = *(const f16x4*)&zh[(size_t)r * CAT2_ + c];
        float4 g4 = *(const float4*)&gx[(size_t)r * 4096 + c];
        float gv[4] = {g4.x, g4.y, g4.z, g4.w};
        #pragma unroll
        for (int q = 0; q < 4; ++q) h[q] = (f16)((float)zh4[q] + gv[q]);
    }
    *(f16x4*)&dh[i4] = h;
}

// zcA = fp16(zc + z0) -> h-plane only
__global__ void zc_conv_k(const float* __restrict__ zc, const float* __restrict__ z0,
                          f16* __restrict__ dh)
{
    size_t i4 = ((size_t)blockIdx.x * 256 + threadIdx.x) * 4;
    if (i4 >= (size_t)MP_ * 1024) return;
    int r = (int)(i4 / 1024), c = (int)(i4 % 1024);
    f16x4 h = {};
    if (r < N_) {
        float4 a4 = *(const float4*)&zc[(size_t)r * 1024 + c];
        float4 b4 = *(const float4*)&z0[(size_t)r * 1024 + c];
        float av[4] = {a4.x, a4.y, a4.z, a4.w};
        float bv[4] = {b4.x, b4.y, b4.z, b4.w};
        #pragma unroll
        for (int q = 0; q < 4; ++q) h[q] = (f16)(av[q] + bv[q]);
    }
    *(f16x4*)&dh[i4] = h;
}

// ---------------- fp32 fallback GEMM ----------------
template<int NPARTS, bool RELU>
__global__ __launch_bounds__(256)
void gemm_k(int M, int Nc, int Kt,
            const float* __restrict__ A0, int w0,
            const float* __restrict__ A1, int w1,
            const float* __restrict__ A2, int w2,
            const float* __restrict__ B, int ldb,
            const float* __restrict__ bias,
            float alpha, const float* __restrict__ D, float dscale,
            float* __restrict__ C, int ldc)
{
    __shared__ __align__(16) float As[16][68];
    __shared__ __align__(16) float Bs[16][68];
    const int tid = threadIdx.x;
    const int tx = tid & 15, ty = tid >> 4;
    const int bm = blockIdx.y * 64, bn = blockIdx.x * 64;
    const int w01 = w0 + w1;
    float acc[4][4] = {};

    for (int kt = 0; kt < Kt; kt += 16) {
        #pragma unroll
        for (int r = 0; r < 4; ++r) {
            int idx = tid + r * 256;
            int m = idx >> 4, kk = idx & 15;
            int row = bm + m, k = kt + kk;
            float v = 0.f;
            if (row < M && k < Kt) {
                if (NPARTS == 1) v = A0[(size_t)row * w0 + k];
                else {
                    if (k < w0) v = A0[(size_t)row * w0 + k];
                    else if (NPARTS == 2 || k < w01) v = A1[(size_t)row * w1 + (k - w0)];
                    else v = A2[(size_t)row * w2 + (k - w01)];
                }
            }
            As[kk][m] = v;
        }
        #pragma unroll
        for (int r = 0; r < 4; ++r) {
            int idx = tid + r * 256;
            int kk = idx >> 6, nn = idx & 63;
            int k = kt + kk, c = bn + nn;
            Bs[kk][nn] = (k < Kt && c < Nc) ? B[(size_t)k * ldb + c] : 0.f;
        }
        __syncthreads();
        #pragma unroll
        for (int kk = 0; kk < 16; ++kk) {
            float4 a4 = *(const float4*)&As[kk][ty * 4];
            float4 b4 = *(const float4*)&Bs[kk][tx * 4];
            float av[4] = {a4.x, a4.y, a4.z, a4.w};
            float bv[4] = {b4.x, b4.y, b4.z, b4.w};
            #pragma unroll
            for (int i = 0; i < 4; ++i)
                #pragma unroll
                for (int j = 0; j < 4; ++j)
                    acc[i][j] = fmaf(av[i], bv[j], acc[i][j]);
        }
        __syncthreads();
    }

    #pragma unroll
    for (int i = 0; i < 4; ++i) {
        int row = bm + ty * 4 + i;
        if (row >= M) continue;
        #pragma unroll
        for (int j = 0; j < 4; ++j) {
            int col = bn + tx * 4 + j;
            if (col >= Nc) continue;
            float val = alpha * acc[i][j];
            if (D)    val += dscale * D[(size_t)row * ldc + col];
            if (bias) val += bias[col];
            if (RELU) val = fmaxf(val, 0.f);
            C[(size_t)row * ldc + col] = val;
        }
    }
}

// ---------------- small kernels ----------------
__global__ void row_dinv_k(const float* __restrict__ zz, float* __restrict__ dinv) {
    __shared__ float red[256];
    int i = blockIdx.x, t = threadIdx.x;
    float s = 0.f;
    for (int j = t; j < N_; j += 256) s += zz[(size_t)i * N_ + j];
    red[t] = s; __syncthreads();
    for (int k = 128; k > 0; k >>= 1) { if (t < k) red[t] += red[t + k]; __syncthreads(); }
    if (t == 0) dinv[i] = 1.0f / sqrtf(red[0] + 1.0f);
}

__global__ void build_MX_k(const float* __restrict__ zz, const float* __restrict__ dinv,
                           float* __restrict__ Mm, float* __restrict__ X) {
    int idx = blockIdx.x * 256 + threadIdx.x;
    if (idx >= N_ * N_) return;
    int i = idx / N_, j = idx - i * N_;
    float diag = (i == j) ? 1.f : 0.f;
    float t = dinv[i] * (zz[idx] + diag) * dinv[j];
    float m = diag - 0.95f * t;
    Mm[idx] = m;
    X[idx]  = 2.f * diag - m;
}

// argmax-loop top-K (fp32 fallback path)
__global__ __launch_bounds__(256) void topk_colnorm_k(const float* __restrict__ X, float* __restrict__ S) {
    __shared__ float v[N_];
    __shared__ float svals[K_];
    __shared__ int   sidx[K_];
    __shared__ float wv[4];
    __shared__ int   wi[4];
    const int j = blockIdx.x, t = threadIdx.x;
    const int lane = t & 63, wid = t >> 6;
    for (int i = t; i < N_; i += 256) v[i] = X[(size_t)i * N_ + j];
    __syncthreads();
    for (int r = 0; r < K_; ++r) {
        float bv = -INFINITY; int bi = N_;
        for (int i = t; i < N_; i += 256) {
            float x = v[i];
            if (x > bv || (x == bv && i < bi)) { bv = x; bi = i; }
        }
        #pragma unroll
        for (int s = 32; s > 0; s >>= 1) {
            float ov = __shfl_xor(bv, s);
            int   oi = __shfl_xor(bi, s);
            if (ov > bv || (ov == bv && oi < bi)) { bv = ov; bi = oi; }
        }
        if (lane == 0) { wv[wid] = bv; wi[wid] = bi; }
        __syncthreads();
        float fv = wv[0]; int fi = wi[0];
        #pragma unroll
        for (int q = 1; q < 4; ++q) {
            float ov = wv[q]; int oi = wi[q];
            if (ov > fv || (ov == fv && oi < fi)) { fv = ov; fi = oi; }
        }
        if (t == 0) { svals[r] = fv; sidx[r] = fi; v[fi] = -INFINITY; }
        __syncthreads();
    }
    float s = (t < K_) ? svals[t] : 0.f;
    #pragma unroll
    for (int q = 32; q > 0; q >>= 1) s += __shfl_xor(s, q);
    if (lane == 0) wv[wid] = s;
    __syncthreads();
    float cs = wv[0] + wv[1] + wv[2] + wv[3];
    if (cs == 0.f) cs = 1.f;
    if (t < K_) S[(size_t)sidx[t] * N_ + j] = svals[t] / cs;
}

__global__ void add_k(const float* __restrict__ a, const float* __restrict__ b,
                      float* __restrict__ c, int n) {
    int i = blockIdx.x * 256 + threadIdx.x;
    if (i < n) c[i] = a[i] + b[i];
}
__global__ void fill_k(float* __restrict__ p, float v, int n) {
    int i = blockIdx.x * 256 + threadIdx.x;
    if (i < n) p[i] = v;
}
__global__ void edge_deg_k(const int* __restrict__ ei, float* __restrict__ deg) {
    int e = blockIdx.x * 256 + threadIdx.x;
    if (e < E_) atomicAdd(&deg[ei[E_ + e]], 1.0f);
}
__global__ void rsqrt_k(float* __restrict__ d, int n) {
    int i = blockIdx.x * 256 + threadIdx.x;
    if (i < n) d[i] = 1.0f / sqrtf(d[i]);
}
__global__ void edge_G_k(const int* __restrict__ ei, const float* __restrict__ dinv,
                         float* __restrict__ G) {
    int e = blockIdx.x * 256 + threadIdx.x;
    if (e < E_) {
        int r = ei[e], c = ei[E_ + e];
        atomicAdd(&G[(size_t)c * N_ + r], dinv[r] * dinv[c]);
    }
}
__global__ void diag_G_k(float* __restrict__ G, const float* __restrict__ dinv) {
    int i = blockIdx.x * 256 + threadIdx.x;
    if (i < N_) G[(size_t)i * N_ + i] += dinv[i] * dinv[i];
}

__global__ __launch_bounds__(1024) void deg_dinv_k(const int* __restrict__ ei,
                                                   float* __restrict__ dinv2) {
    __shared__ float deg[N_];
    int t = threadIdx.x;
    for (int i = t; i < N_; i += 1024) deg[i] = 1.f;
    __syncthreads();
    for (int e = t; e < E_; e += 1024) atomicAdd(&deg[ei[E_ + e]], 1.f);
    __syncthreads();
    for (int i = t; i < N_; i += 1024) dinv2[i] = 1.f / sqrtf(deg[i]);
}
__global__ void edge_diag_G_k(const int* __restrict__ ei, const float* __restrict__ dinv,
                              float* __restrict__ G) {
    int e = blockIdx.x * 256 + threadIdx.x;
    if (e < E_) {
        int r = ei[e], c = ei[E_ + e];
        atomicAdd(&G[(size_t)c * N_ + r], dinv[r] * dinv[c]);
    } else {
        int i = e - E_;
        if (i < N_) atomicAdd(&G[(size_t)i * N_ + i], dinv[i] * dinv[i]);
    }
}

// ===================== host-side =====================
struct HL { f16* h; f16* l; };
static const HL HL0 = {nullptr, nullptr};

static inline void g16(hipStream_t st, bool relu, bool dual, bool wide,
                       int M, int Nc, int Kt, int split,
                       HL A, int lda, HL B, int ldb,
                       const float* bias, float alpha,
                       const float* D, int ldd, float dscale,
                       float* C, int ldc,
                       HL oA, int ldoa, HL oB, int ldob, float* P)
{
    const int BN = wide ? 256 : 128;
    const int gx = (Nc + BN - 1) / BN, gy = (M + 127) / 128;
    const int totalSteps = Kt >> 5;
    const int chunk = (totalSteps + split - 1) / split;
    const int Mp = gy * 128, Ncp = gx * BN;
    dim3 grid(gx, gy, split), blk(512);
    float* Pp = (split > 1) ? P : nullptr;
#define CALL_G16(RL, DU, WI) gemm_f16x2<RL, DU, WI><<<grid, blk, 0, st>>>(M, Nc, Kt, chunk, \
        A.h, A.l, lda, B.h, B.l, ldb, bias, alpha, D, ldd, dscale, C, ldc, \
        oA.h, oA.l, ldoa, oB.h, oB.l, ldob, Pp, Mp, Ncp)
    if (dual)      { if (relu) CALL_G16(true, true, false);  else CALL_G16(false, true, false); }
    else if (wide) { if (relu) CALL_G16(true, false, true);  else CALL_G16(false, false, true); }
    else           { if (relu) CALL_G16(true, false, false); else CALL_G16(false, false, false); }
#undef CALL_G16
    if (split > 1) {
        unsigned tot = (unsigned)(M * Nc);
        dim3 cg((tot + 255) / 256);
        if (relu)
            combine_k<true><<<cg, 256, 0, st>>>(M, Nc, split, Mp, Ncp, P, bias, alpha,
                D, ldd, dscale, C, ldc, oA.h, oA.l, ldoa, oB.h, oB.l, ldob);
        else
            combine_k<false><<<cg, 256, 0, st>>>(M, Nc, split, Mp, Ncp, P, bias, alpha,
                D, ldd, dscale, C, ldc, oA.h, oA.l, ldoa, oB.h, oB.l, ldob);
    }
}

static inline void convA(hipStream_t st, const float* src, int R, int C, int lds,
                         HL d, int ldd, int Rp, int Cp)
{
    size_t total4 = (size_t)Rp * Cp / 4;
    conv_A_k<<<(int)((total4 + 255) / 256), 256, 0, st>>>(src, R, C, lds, d.h, d.l, ldd, Rp, Cp);
}
static inline void convBt(hipStream_t st, const float* src, int K, int N,
                          HL d, int ldk, int Kp, int Np)
{
    dim3 grid((Kp + 31) / 32, (Np + 63) / 64), blk(256);
    conv_Bt_k<<<grid, blk, 0, st>>>(src, K, N, d.h, d.l, ldk, Kp, Np);
}

static inline void launch_gemm_f32(hipStream_t st, bool relu, int nparts,
                                   int M, int Nc, int Kt,
                                   const float* A0, int w0, const float* A1, int w1,
                                   const float* A2, int w2,
                                   const float* B, int ldb, const float* bias,
                                   float alpha, const float* D, float dscale,
                                   float* C, int ldc)
{
    dim3 g((Nc + 63) / 64, (M + 63) / 64), b(256);
#define CALL_GEMM(NP, RL) gemm_k<NP, RL><<<g, b, 0, st>>>(M, Nc, Kt, A0, w0, A1, w1, A2, w2, B, ldb, bias, alpha, D, dscale, C, ldc)
    if (relu) { if (nparts == 1) CALL_GEMM(1, true); else if (nparts == 2) CALL_GEMM(2, true); else CALL_GEMM(3, true); }
    else      { if (nparts == 1) CALL_GEMM(1, false); else if (nparts == 2) CALL_GEMM(2, false); else CALL_GEMM(3, false); }
#undef CALL_GEMM
}

// ---- fast-path workspace layout ----
static constexpr size_t catA1_e = (size_t)MP_ * 8192;
static constexpr size_t jw1Bt_e = (size_t)2048 * 8192;
static constexpr size_t jw2Bt_e = (size_t)MP_ * 2048;
static constexpr size_t h1A_e   = (size_t)MP_ * 2048;
static constexpr size_t nb_e    = (size_t)MP_ * KP1_;
static constexpr size_t ec1Bt_e = (size_t)4096 * 8192;
static constexpr size_t drBt_e  = (size_t)1024 * 4096;
static constexpr size_t g1Bt_e  = (size_t)2048 * 4096;
static constexpr size_t g2Bt_e  = (size_t)1024 * 2048;
static constexpr size_t ec2Bt_e = (size_t)1024 * 7168;
static constexpr size_t ec3Bt_e = (size_t)512 * 1024;
static constexpr size_t hg1Bt_e = (size_t)2048 * KP1_;
static constexpr size_t hg2Bt_e = (size_t)1024 * KP1_;
static constexpr size_t catA2_e = (size_t)MP_ * 8192;
static constexpr size_t SA_e    = nb_e;
static constexpr size_t GA_e    = nb_e;
static constexpr size_t xBt_e   = (size_t)4096 * KP1_;
static constexpr size_t zgxA_e  = (size_t)MP_ * 4096;
static constexpr size_t cat3_e  = (size_t)MP_ * 7168;
static constexpr size_t zcA_e   = (size_t)MP_ * 1024;

static constexpr size_t u_catA1 = 0;
static constexpr size_t u_jw1Bt = u_catA1 + 2 * catA1_e;
static constexpr size_t u_jw2Bt = u_jw1Bt + 2 * jw1Bt_e;
static constexpr size_t u_h1A   = u_jw2Bt + 2 * jw2Bt_e;
static constexpr size_t u_nb0   = u_h1A + 2 * h1A_e;
static constexpr size_t u_nb1   = u_nb0 + 2 * nb_e;
static constexpr size_t u_nb2   = u_nb1 + 2 * nb_e;
static constexpr size_t u_nb3   = u_nb2 + 2 * nb_e;
static constexpr size_t u_nb4   = u_nb3 + 2 * nb_e;
static constexpr size_t u_nb5   = u_nb4 + 2 * nb_e;
static constexpr size_t UNION_F16 = u_nb5 + 2 * nb_e;
static_assert(2 * ec1Bt_e <= UNION_F16, "ec1Bt alias");
static constexpr size_t u_drBt  = 0;
static constexpr size_t u_g1Bt  = u_drBt + 2 * drBt_e;
static constexpr size_t u_g2Bt  = u_g1Bt + 2 * g1Bt_e;
static constexpr size_t u_ec2Bt = u_g2Bt + 2 * g2Bt_e;
static constexpr size_t u_ec3Bt = u_ec2Bt + 2 * ec2Bt_e;
static constexpr size_t u_hg1Bt = u_ec3Bt + 2 * ec3Bt_e;
static constexpr size_t u_hg2Bt = u_hg1Bt + 2 * hg1Bt_e;
static_assert(u_hg2Bt + 2 * hg2Bt_e <= UNION_F16, "phase3 alias");

static constexpr size_t o_catA2 = 0;
static constexpr size_t o_SA    = o_catA2 + 2 * catA2_e;
static constexpr size_t o_GA    = o_SA + 2 * SA_e;
static constexpr size_t o_xBt   = o_GA + 2 * GA_e;
static constexpr size_t o_zgxA  = o_xBt + 2 * xBt_e;
static constexpr size_t o_cat3  = o_zgxA + 2 * zgxA_e;
static constexpr size_t o_zcA   = o_cat3 + 2 * cat3_e;
static constexpr size_t OUT_F16 = o_zcA + 2 * zcA_e;

static constexpr size_t NN_     = (size_t)N_ * N_;
static constexpr size_t F16_TOTAL = UNION_F16 + OUT_F16;
static constexpr size_t f_zz = 0, f_Mm = NN_, f_X0 = 2 * NN_, f_X1 = 3 * NN_,
                        f_S = 4 * NN_, f_G = 5 * NN_, f_z0 = 6 * NN_,
                        f_zc = f_z0 + (size_t)N_ * 1024,
                        f_zf = f_zc + (size_t)N_ * 1024,
                        f_dinv = f_zf + (size_t)N_ * 512,
                        f_dinv2 = f_dinv + 1028,
                        F32_TOTAL = f_dinv2 + 1028;
static constexpr size_t P_e = (size_t)2 * MP_ * 4096;  // split-K partials cap (9.44M floats)
static constexpr size_t FAST_WS_BYTES = F16_TOTAL * 2 + (F32_TOTAL + P_e) * 4;
static_assert((size_t)6 * 1152 * 1152 <= P_e, "pchain partial fit");
static_assert((size_t)8 * 1152 * 1024 <= P_e, "wide split8 fit");
static_assert((size_t)4 * 1152 * 2048 <= P_e, "wide split4 fit");

static void run_fast(void* const* d_in, float* out, void* d_ws, hipStream_t st)
{
    const float* x    = (const float*)d_in[0];
    const float* gx   = (const float*)d_in[1];
    const int*   ei   = (const int*)d_in[2];
    const float* jw1  = (const float*)d_in[3];
    const float* jb1  = (const float*)d_in[4];
    const float* jw2  = (const float*)d_in[5];
    const float* jb2  = (const float*)d_in[6];
    const float* ec1w = (const float*)d_in[7];
    const float* ec1b = (const float*)d_in[8];
    const float* drw  = (const float*)d_in[9];
    const float* drb  = (const float*)d_in[10];
    const float* g1w  = (const float*)d_in[11];
    const float* g1b  = (const float*)d_in[12];
    const float* g2w  = (const float*)d_in[13];
    const float* g2b  = (const float*)d_in[14];
    const float* ec2w = (const float*)d_in[15];
    const float* ec2b = (const float*)d_in[16];
    const float* ec3w = (const float*)d_in[17];
    const float* ec3b = (const float*)d_in[18];
    const float* outw = (const float*)d_in[19];
    const float* outb = (const float*)d_in[20];

    f16*   fb   = (f16*)d_ws;
    float* f32b = (float*)((char*)d_ws + F16_TOTAL * 2);
    float* P    = f32b + F32_TOTAL;

    auto mk = [&](size_t off, size_t elems) { return HL{fb + off, fb + off + elems}; };
    HL catA1 = mk(u_catA1, catA1_e), jw1Bt = mk(u_jw1Bt, jw1Bt_e),
       jw2Bt = mk(u_jw2Bt, jw2Bt_e), h1A = mk(u_h1A, h1A_e);
    HL pA[2]  = {mk(u_nb0, nb_e), mk(u_nb1, nb_e)};
    HL aA[2]  = {mk(u_nb2, nb_e), mk(u_nb3, nb_e)};
    HL aBt[2] = {mk(u_nb4, nb_e), mk(u_nb5, nb_e)};
    HL ec1Bt = mk(0, ec1Bt_e);
    HL drBt = mk(u_drBt, drBt_e), g1Bt = mk(u_g1Bt, g1Bt_e), g2Bt = mk(u_g2Bt, g2Bt_e),
       ec2Bt = mk(u_ec2Bt, ec2Bt_e), ec3Bt = mk(u_ec3Bt, ec3Bt_e),
       hg1Bt = mk(u_hg1Bt, hg1Bt_e), hg2Bt = mk(u_hg2Bt, hg2Bt_e);
    HL catA2 = mk(UNION_F16 + o_catA2, catA2_e), SA = mk(UNION_F16 + o_SA, SA_e),
       GA = mk(UNION_F16 + o_GA, GA_e), xBt = mk(UNION_F16 + o_xBt, xBt_e),
       zgxA = mk(UNION_F16 + o_zgxA, zgxA_e), cat3 = mk(UNION_F16 + o_cat3, cat3_e),
       zcA = mk(UNION_F16 + o_zcA, zcA_e);
    float *zz = f32b + f_zz, *XT = f32b + f_Mm, *Pf[2] = {f32b + f_X0, f32b + f_X1},
          *S = f32b + f_S, *G = f32b + f_G, *z0 = f32b + f_z0, *zc = f32b + f_zc,
          *zf = f32b + f_zf, *dinv = f32b + f_dinv, *dinv2 = f32b + f_dinv2;

    // zero all 6 P-chain hi/lo pair buffers (K/M pads must be zero)
    hipMemsetAsync(fb + u_nb0, 0, (UNION_F16 - u_nb0) * sizeof(f16), st);

    // 1) h1 = relu([x|gx] @ jw1 + jb1)  -> h1A   (DUAL, split 4)
    {
        size_t t4 = (size_t)MP_ * 8192 / 4;
        cat2_conv_k<<<(int)((t4 + 255) / 256), 256, 0, st>>>(x, gx, catA1.h, catA1.l);
    }
    convBt(st, jw1, 8192, 2048, jw1Bt, 8192, 8192, 2048);
    g16(st, true, true, false, 1026, 2048, 8192, 4, catA1, 8192, jw1Bt, 8192, jb1, 1.f,
        nullptr, 0, 0.f, nullptr, 0, h1A, 2048, HL0, 0, P);
    // 2) zz = relu(h1 @ jw2 + jb2)   (DUAL, split 7)
    convBt(st, jw2, 2048, 1026, jw2Bt, 2048, 2048, MP_);
    g16(st, true, true, false, 1026, 1026, 2048, 7, h1A, 2048, jw2Bt, 2048, jb2, 1.f,
        nullptr, 0, 0.f, zz, 1026, HL0, 0, HL0, 0, P);
    // 3-4) degree + A forms + P_1
    row_dinv_k<<<N_, 256, 0, st>>>(zz, dinv);
    build_A_k<<<(int)((NN_ + 255) / 256), 256, 0, st>>>(zz, dinv,
        aA[0].h, aA[0].l, aBt[0].h, aBt[0].l, Pf[0], pA[0].h, pA[0].l);
    // 5) P-chain: stages cover A^0..A^255 (tail ~2e-6 relative, dropped)
    {
        const int PS = 3, PCH = 11;   // 33 K-steps = 3 x 11
        dim3 cg((unsigned)((NN_ + 255) / 256));
        // stage 1: square only
        pchain_k<<<dim3(9, 9, PS), 512, 0, st>>>(1, PS, PCH,
            nullptr, nullptr, aA[0].h, aA[0].l, aBt[0].h, aBt[0].l, P);
        pchain_combine_k<<<cg, 256, 0, st>>>(PS, 0, 1, P,
            nullptr, nullptr, nullptr, nullptr, nullptr,
            aA[1].h, aA[1].l, aBt[1].h, aBt[1].l);
        int ac = 1, pc = 0;
        // stages 2..7: update || square  (use A^2..A^64, produce up to A^128)
        for (int k = 2; k <= 7; ++k) {
            pchain_k<<<dim3(9, 9, 2 * PS), 512, 0, st>>>(0, PS, PCH,
                pA[pc].h, pA[pc].l, aA[ac].h, aA[ac].l, aBt[ac].h, aBt[ac].l, P);
            pchain_combine_k<<<cg, 256, 0, st>>>(PS, 1, 1, P,
                Pf[pc], Pf[1 - pc], pA[1 - pc].h, pA[1 - pc].l, nullptr,
                aA[1 - ac].h, aA[1 - ac].l, aBt[1 - ac].h, aBt[1 - ac].l);
            pc ^= 1; ac ^= 1;
        }
        // stage 8: final update (uses A^128) -> fp32 X transposed for topk
        pchain_k<<<dim3(9, 9, PS), 512, 0, st>>>(0, PS, PCH,
            pA[pc].h, pA[pc].l, nullptr, nullptr, aBt[ac].h, aBt[ac].l, P);
        pchain_combine_k<<<cg, 256, 0, st>>>(PS, 1, 0, P,
            Pf[pc], Pf[1 - pc], nullptr, nullptr, XT,
            nullptr, nullptr, nullptr, nullptr);
    }
    // 6-7) topk (bitonic sort on XT rows) + colnorm
    hipMemsetAsync(S, 0, NN_ * sizeof(float), st);
    topk_sort_k<<<N_, 256, 0, st>>>(XT, S);
    // 8) xn = S @ x  -> catA2[:, :4096] h-only   (DUAL, split 2)
    convA(st, S, N_, N_, N_, SA, KP1_, MP_, KP1_);
    convBt(st, x, 1026, 4096, xBt, KP1_, KP1_, 4096);
    g16(st, false, true, false, 1026, 4096, KP1_, 2, SA, KP1_, xBt, KP1_, nullptr, 1.f,
        nullptr, 0, 0.f, nullptr, 0, HL{catA2.h, nullptr}, 8192, HL0, 0, P);
    convA(st, gx, N_, 4096, 4096, HL{catA2.h + 4096, nullptr}, 8192, MP_, 4096);
    // 9) z = relu([xn|gx] @ ec1w + b) -> cat3[:, :4096] h-only   (WIDE, split 2)
    convBt(st, ec1w, 8192, 4096, HL{ec1Bt.h, nullptr}, 8192, 8192, 4096);
    g16(st, true, false, true, 1026, 4096, 8192, 2, catA2, 8192, ec1Bt, 8192, ec1b, 1.f,
        nullptr, 0, 0.f, nullptr, 0, HL{cat3.h, nullptr}, 7168, HL0, 0, P);
    // 12) dense GCN aggregation matrix G
    deg_dinv_k<<<1, 1024, 0, st>>>(ei, dinv2);
    hipMemsetAsync(G, 0, NN_ * sizeof(float), st);
    edge_diag_G_k<<<(E_ + N_ + 255) / 256, 256, 0, st>>>(ei, dinv2, G);
    convA(st, G, N_, N_, N_, HL{GA.h, nullptr}, KP1_, MP_, KP1_);
    // 10) z0 = z @ drw + drb   (WIDE, split 8)
    convBt(st, drw, 4096, 1024, HL{drBt.h, nullptr}, 4096, 4096, 1024);
    g16(st, false, false, true, 1026, 1024, 4096, 8, HL{cat3.h, nullptr}, 7168,
        drBt, 4096, drb, 1.f, nullptr, 0, 0.f, z0, 1024, HL0, 0, HL0, 0, P);
    // 11) zgx = fp16(z) + gx  (h-only)
    {
        size_t t4 = (size_t)MP_ * 4096 / 4;
        zgx_conv_k<<<(int)((t4 + 255) / 256), 256, 0, st>>>(cat3.h, gx, zgxA.h);
    }
    // 13') hg1^T = g1w^T @ zgx^T -> hg1Bt h-only   (SINGLE, split 4)
    convBt(st, g1w, 4096, 2048, HL{g1Bt.h, nullptr}, 4096, 4096, 2048);
    hipMemsetAsync(fb + u_hg1Bt, 0, (2 * hg1Bt_e + 2 * hg2Bt_e) * sizeof(f16), st);
    g16(st, false, false, false, 2048, 1026, 4096, 4, g1Bt, 4096, zgxA, 4096, nullptr, 1.f,
        nullptr, 0, 0.f, nullptr, 0, HL{hg1Bt.h, nullptr}, KP1_, HL0, 0, P);
    // 14) z1 = relu(G @ hg1 + g1b) -> cat3[:, 4096:6144] h-only   (WIDE, split 4)
    g16(st, true, false, true, 1026, 2048, KP1_, 4, GA, KP1_, hg1Bt, KP1_, g1b, 1.f,
        nullptr, 0, 0.f, nullptr, 0, HL{cat3.h + 4096, nullptr}, 7168, HL0, 0, P);
    // 15') hg2^T = g2w^T @ z1^T -> hg2Bt h-only   (SINGLE, split 8)
    convBt(st, g2w, 2048, 1024, HL{g2Bt.h, nullptr}, 2048, 2048, 1024);
    g16(st, false, false, false, 1024, 1026, 2048, 8, g2Bt, 2048,
        HL{cat3.h + 4096, nullptr}, 7168, nullptr, 1.f, nullptr, 0, 0.f,
        nullptr, 0, HL{hg2Bt.h, nullptr}, KP1_, HL0, 0, P);
    // 16) z2 = relu(G @ hg2 + g2b) -> cat3[:, 6144:7168] h-only   (WIDE, split 8)
    g16(st, true, false, true, 1026, 1024, KP1_, 8, GA, KP1_, hg2Bt, KP1_, g2b, 1.f,
        nullptr, 0, 0.f, nullptr, 0, HL{cat3.h + 6144, nullptr}, 7168, HL0, 0, P);
    // 17) zc = relu([z|z1|z2] @ ec2w + b)   (WIDE, split 8)
    convBt(st, ec2w, 7168, 1024, HL{ec2Bt.h, nullptr}, 7168, 7168, 1024);
    g16(st, true, false, true, 1026, 1024, 7168, 8, HL{cat3.h, nullptr}, 7168,
        ec2Bt, 7168, ec2b, 1.f, nullptr, 0, 0.f, zc, 1024, HL0, 0, HL0, 0, P);
    // 18-19) zf = relu((zc + z0) @ ec3w + b)   (SINGLE, split 8)
    {
        size_t t4 = (size_t)MP_ * 1024 / 4;
        zc_conv_k<<<(int)((t4 + 255) / 256), 256, 0, st>>>(zc, z0, zcA.h);
    }
    convBt(st, ec3w, 1024, 512, HL{ec3Bt.h, nullptr}, 1024, 1024, 512);
    g16(st, true, false, false, 1026, 512, 1024, 8, HL{zcA.h, nullptr}, 1024,
        ec3Bt, 1024, ec3b, 1.f, nullptr, 0, 0.f, zf, 512, HL0, 0, HL0, 0, P);
    // 20) out = zf @ outw + outb  (tiny, fp32)
    launch_gemm_f32(st, false, 1, N_, NL_, OUTS_, zf, OUTS_, nullptr, 0, nullptr, 0,
                    outw, NL_, outb, 1.f, nullptr, 0.f, out, NL_);
}

static void run_ref(void* const* d_in, float* out, void* d_ws, hipStream_t stream)
{
    const float* x    = (const float*)d_in[0];
    const float* gx   = (const float*)d_in[1];
    const int*   ei   = (const int*)d_in[2];
    const float* jw1  = (const float*)d_in[3];
    const float* jb1  = (const float*)d_in[4];
    const float* jw2  = (const float*)d_in[5];
    const float* jb2  = (const float*)d_in[6];
    const float* ec1w = (const float*)d_in[7];
    const float* ec1b = (const float*)d_in[8];
    const float* drw  = (const float*)d_in[9];
    const float* drb  = (const float*)d_in[10];
    const float* g1w  = (const float*)d_in[11];
    const float* g1b  = (const float*)d_in[12];
    const float* g2w  = (const float*)d_in[13];
    const float* g2b  = (const float*)d_in[14];
    const float* ec2w = (const float*)d_in[15];
    const float* ec2b = (const float*)d_in[16];
    const float* ec3w = (const float*)d_in[17];
    const float* ec3b = (const float*)d_in[18];
    const float* outw = (const float*)d_in[19];
    const float* outb = (const float*)d_in[20];

    float* ws = (float*)d_ws;
    size_t off = 0;
    float* H1buf = ws + off; off += (size_t)N_ * JH_;
    float* ZZ    = ws + off; off += NN_;
    float* Mm    = ws + off; off += NN_;
    float* Xa    = ws + off; off += NN_;
    float* Xb    = ws + off; off += NN_;
    float* S     = ws + off; off += NN_;
    float* G     = ws + off; off += NN_;
    float* dinv  = ws + off; off += 1028;
    float* dinv2 = ws + off; off += 1028;
    float* XN    = ws + off; off += (size_t)N_ * H0_;
    float* Z     = ws + off; off += (size_t)N_ * H0_;
    float* ZGX   = ws + off; off += (size_t)N_ * H0_;
    float* Z0    = ws + off; off += (size_t)N_ * H2_;
    float* HG1   = ws + off; off += (size_t)N_ * H1_;
    float* Z1    = ws + off; off += (size_t)N_ * H1_;
    float* HG2   = ws + off; off += (size_t)N_ * H2_;
    float* Z2    = ws + off; off += (size_t)N_ * H2_;
    float* ZC    = ws + off; off += (size_t)N_ * H2_;
    float* ZF    = ws + off; off += (size_t)N_ * OUTS_;

    launch_gemm_f32(stream, true, 2, N_, JH_, INS_, x, DX_, gx, DG_, nullptr, 0,
                    jw1, JH_, jb1, 1.f, nullptr, 0.f, H1buf, JH_);
    launch_gemm_f32(stream, true, 1, N_, N_, JH_, H1buf, JH_, nullptr, 0, nullptr, 0,
                    jw2, N_, jb2, 1.f, nullptr, 0.f, ZZ, N_);
    row_dinv_k<<<N_, 256, 0, stream>>>(ZZ, dinv);
    build_MX_k<<<(int)((NN_ + 255) / 256), 256, 0, stream>>>(ZZ, dinv, Mm, Xa);
    float* Xcur = Xa; float* Xalt = Xb; float* W = H1buf;
    for (int it = 0; it < 9; ++it) {
        launch_gemm_f32(stream, false, 1, N_, N_, N_, Mm, N_, nullptr, 0, nullptr, 0,
                        Xcur, N_, nullptr, 1.f, nullptr, 0.f, W, N_);
        launch_gemm_f32(stream, false, 1, N_, N_, N_, Xcur, N_, nullptr, 0, nullptr, 0,
                        W, N_, nullptr, -1.f, Xcur, 2.f, Xalt, N_);
        float* tmp = Xcur; Xcur = Xalt; Xalt = tmp;
    }
    hipMemsetAsync(S, 0, NN_ * sizeof(float), stream);
    topk_colnorm_k<<<N_, 256, 0, stream>>>(Xcur, S);
    launch_gemm_f32(stream, false, 1, N_, DX_, N_, S, N_, nullptr, 0, nullptr, 0,
                    x, DX_, nullptr, 1.f, nullptr, 0.f, XN, DX_);
    launch_gemm_f32(stream, true, 2, N_, H0_, INS_, XN, DX_, gx, DG_, nullptr, 0,
                    ec1w, H0_, ec1b, 1.f, nullptr, 0.f, Z, H0_);
    launch_gemm_f32(stream, false, 1, N_, H2_, H0_, Z, H0_, nullptr, 0, nullptr, 0,
                    drw, H2_, drb, 1.f, nullptr, 0.f, Z0, H2_);
    add_k<<<(int)(((size_t)N_ * H0_ + 255) / 256), 256, 0, stream>>>(Z, gx, ZGX, N_ * H0_);
    fill_k<<<(N_ + 255) / 256, 256, 0, stream>>>(dinv2, 1.0f, N_);
    edge_deg_k<<<(E_ + 255) / 256, 256, 0, stream>>>(ei, dinv2);
    rsqrt_k<<<(N_ + 255) / 256, 256, 0, stream>>>(dinv2, N_);
    hipMemsetAsync(G, 0, NN_ * sizeof(float), stream);
    edge_G_k<<<(E_ + 255) / 256, 256, 0, stream>>>(ei, dinv2, G);
    diag_G_k<<<(N_ + 255) / 256, 256, 0, stream>>>(G, dinv2);
    launch_gemm_f32(stream, false, 1, N_, H1_, H0_, ZGX, H0_, nullptr, 0, nullptr, 0,
                    g1w, H1_, nullptr, 1.f, nullptr, 0.f, HG1, H1_);
    launch_gemm_f32(stream, true, 1, N_, H1_, N_, G, N_, nullptr, 0, nullptr, 0,
                    HG1, H1_, g1b, 1.f, nullptr, 0.f, Z1, H1_);
    launch_gemm_f32(stream, false, 1, N_, H2_, H1_, Z1, H1_, nullptr, 0, nullptr, 0,
                    g2w, H2_, nullptr, 1.f, nullptr, 0.f, HG2, H2_);
    launch_gemm_f32(stream, true, 1, N_, H2_, N_, G, N_, nullptr, 0, nullptr, 0,
                    HG2, H2_, g2b, 1.f, nullptr, 0.f, Z2, H2_);
    launch_gemm_f32(stream, true, 3, N_, H2_, CAT2_, Z, H0_, Z1, H1_, Z2, H2_,
                    ec2w, H2_, ec2b, 1.f, nullptr, 0.f, ZC, H2_);
    add_k<<<(int)(((size_t)N_ * H2_ + 255) / 256), 256, 0, stream>>>(ZC, Z0, ZC, N_ * H2_);
    launch_gemm_f32(stream, true, 1, N_, OUTS_, H2_, ZC, H2_, nullptr, 0, nullptr, 0,
                    ec3w, OUTS_, ec3b, 1.f, nullptr, 0.f, ZF, OUTS_);
    launch_gemm_f32(stream, false, 1, N_, NL_, OUTS_, ZF, OUTS_, nullptr, 0, nullptr, 0,
                    outw, NL_, outb, 1.f, nullptr, 0.f, out, NL_);
}

extern "C" void kernel_launch(void* const* d_in, const int* in_sizes, int n_in,
                              void* d_out, int out_size, void* d_ws, size_t ws_size,
                              hipStream_t stream)
{
    (void)in_sizes; (void)n_in; (void)out_size;
    if (ws_size >= FAST_WS_BYTES + 4096)
        run_fast(d_in, (float*)d_out, d_ws, stream);
    else
        run_ref(d_in, (float*)d_out, d_ws, stream);
}